// Round 11
// baseline (73.706 us; speedup 1.0000x reference)
//
#include <hip/hip_runtime.h>

#define N_ATOMS 250000
#define NR 8
#define BLK 512          // threads per block == atoms per block
#define NP 36            // tril pairs
#define NBLK ((N_ATOMS + BLK - 1) / BLK)   // 489

typedef float f4 __attribute__((ext_vector_type(4)));

// R10 writeout-aggregation pushed to 2 KB: 512 atoms/block, single LDS buffer
// [36][512], 2 raw barriers/pass, each (p,t) region written by ONE wave as
// TWO back-to-back 1 KB NT bursts. Read side = R7's two-half m2 bursts to
// stay <=128 VGPR at (512,2).
__global__ __launch_bounds__(BLK, 2) void moment_contr_kernel(
    const float* __restrict__ m1,   // [A, 8, 3]
    const float* __restrict__ m2,   // [A, 8, 3, 3]
    float* __restrict__ out)        // out[p*2000000 + t*250000 + a]
{
    __shared__ float sbuf[NP][BLK];   // 72 KB -> 2 blocks/CU

    // --- bijective XCD-chunked swizzle (489 % 8 != 0) ---
    const int orig = blockIdx.x;
    const int q = NBLK / 8, r = NBLK % 8;      // 61, 1
    const int xcd = orig & 7;
    const int wgid = (xcd < r ? xcd * (q + 1)
                              : r * (q + 1) + (xcd - r) * q) + (orig >> 3);

    const int tid  = threadIdx.x;
    const int wid  = tid >> 6;      // 0..7
    const int lane = tid & 63;
    const long long block_base = (long long)wgid * BLK;
    const long long a = block_base + tid;
    const bool live = (a < N_ATOMS);

    // wave w owns regions [pstart, pstart + pcnt): {5,5,5,5,4,4,4,4}
    const int pstart = (wid < 4) ? 5 * wid : 20 + 4 * (wid - 4);
    const int pcnt   = (wid < 4) ? 5 : 4;

    // ---- m1[a]: 24 floats, VGPR-resident throughout ----
    float m1v[24];
    if (live) {
        const f4* p1 = reinterpret_cast<const f4*>(m1 + (size_t)a * 24);
        #pragma unroll
        for (int k = 0; k < 6; ++k) {
            f4 v = p1[k];
            m1v[4*k+0] = v.x; m1v[4*k+1] = v.y;
            m1v[4*k+2] = v.z; m1v[4*k+3] = v.w;
        }
    } else {
        #pragma unroll
        for (int k = 0; k < 24; ++k) m1v[k] = 0.f;
    }

    const float* m2a = m2 + (size_t)a * 72;   // 288 B/atom, 16B-aligned

    #pragma unroll
    for (int th = 0; th < 2; ++th) {
        // ---- burst-load half of m2: 36 floats = 9x dwordx4 ----
        float m2h[36];
        if (live) {
            const f4* ph = reinterpret_cast<const f4*>(m2a + th * 36);
            #pragma unroll
            for (int k = 0; k < 9; ++k) {
                f4 v = ph[k];
                m2h[4*k+0] = v.x; m2h[4*k+1] = v.y;
                m2h[4*k+2] = v.z; m2h[4*k+3] = v.w;
            }
        } else {
            #pragma unroll
            for (int k = 0; k < 36; ++k) m2h[k] = 0.f;
        }

        #pragma unroll
        for (int t4 = 0; t4 < 4; ++t4) {
            const int t = th * 4 + t4;

            // B[s][i] = sum_j m1[s,j] * m2[t,i,j]
            float B[24];
            #pragma unroll
            for (int s = 0; s < NR; ++s) {
                #pragma unroll
                for (int i = 0; i < 3; ++i) {
                    B[s*3+i] = m1v[s*3+0] * m2h[t4*9 + i*3 + 0]
                             + m1v[s*3+1] * m2h[t4*9 + i*3 + 1]
                             + m1v[s*3+2] * m2h[t4*9 + i*3 + 2];
                }
            }

            // contr[r,s,t] -> LDS[p][tid]; p = r*(r+1)/2 + s (tril order)
            #pragma unroll
            for (int rr = 0; rr < NR; ++rr) {
                #pragma unroll
                for (int s = 0; s <= rr; ++s) {
                    const int p = rr*(rr+1)/2 + s;
                    sbuf[p][tid] = m1v[rr*3+0] * B[s*3+0]
                                 + m1v[rr*3+1] * B[s*3+1]
                                 + m1v[rr*3+2] * B[s*3+2];
                }
            }

            // stage complete -> rendezvous. Raw barrier: NO vmcnt drain, so
            // prior NT stores stay in flight.
            asm volatile("s_waitcnt lgkmcnt(0)\n\ts_barrier" ::: "memory");

            // ---- cooperative writeout: wave wid owns pcnt consecutive
            // regions; each region = 512 floats = 2 back-to-back 1 KB NT
            // dwordx4 bursts (2 KB sequential, single owner).
            for (int k = 0; k < 5; ++k) {
                if (k < pcnt) {
                    const int p = pstart + k;
                    #pragma unroll
                    for (int half = 0; half < 2; ++half) {
                        const int sub = half * 256 + 4 * lane;
                        const long long g = block_base + sub;
                        if (g + 4 <= N_ATOMS) {   // N%4==0: exact f4 guard
                            f4 v = *reinterpret_cast<const f4*>(&sbuf[p][sub]);
                            __builtin_nontemporal_store(
                                v, reinterpret_cast<f4*>(
                                    out + (size_t)p * (NR * N_ATOMS)
                                        + (size_t)t * N_ATOMS + g));
                        }
                    }
                }
            }

            // reuse guard: ds_read->store reg dependency already ordered the
            // LDS reads; just rendezvous before next pass overwrites sbuf.
            asm volatile("s_barrier" ::: "memory");
        }
    }
}

extern "C" void kernel_launch(void* const* d_in, const int* in_sizes, int n_in,
                              void* d_out, int out_size, void* d_ws, size_t ws_size,
                              hipStream_t stream) {
    const float* m1 = (const float*)d_in[0];
    const float* m2 = (const float*)d_in[1];
    float* out = (float*)d_out;

    hipLaunchKernelGGL(moment_contr_kernel, dim3(NBLK), dim3(BLK), 0, stream,
                       m1, m2, out);
}